// Round 1
// baseline (369.533 us; speedup 1.0000x reference)
//
#include <hip/hip_runtime.h>
#include <hip/hip_bf16.h>

#define BB   16384
#define F    40
#define D    64
#define E    64
#define LDK  72      // padded LDS row stride (elements); 144 B = 9*16 B -> uniform superbank spread
#define WAVES 4
#define ITER  4

typedef __bf16 bf16;
typedef __bf16 bf16x8 __attribute__((ext_vector_type(8)));
typedef __bf16 bf16x4 __attribute__((ext_vector_type(4)));
typedef float  f32x4  __attribute__((ext_vector_type(4)));

// MFMA 16x16x32 bf16 layouts (HW-verified per guide):
//   A-frag: lane holds A[m = lane&15][k = (lane>>4)*8 + j], j=0..7 (contiguous in k)
//   B-frag: lane holds B[k = (lane>>4)*8 + j][n = lane&15]  (i.e. B^T row-major, contiguous in k)
//   C/D   : lane holds C[row = (lane>>4)*4 + r][col = lane&15], r=0..3

__global__ __launch_bounds__(256, 1)
void attn_fused(const float* __restrict__ X,
                const float* __restrict__ Wq,
                const float* __restrict__ Wk,
                const float* __restrict__ Wv,
                const float* __restrict__ Wr,
                float* __restrict__ Out)
{
    // Declaration order matters only for tidiness; padded row counts (48) make
    // all "garbage row" reads land inside the owning buffer.
    __shared__ bf16 WT[4][E * LDK];      // WT[w][e*LDK + d]  (W transposed, bf16)
    __shared__ bf16 QB[WAVES][48 * LDK]; // per-wave: q rows, later P rows
    __shared__ bf16 KB[WAVES][48 * LDK]; // per-wave: k rows
    __shared__ bf16 VT[WAVES][E * LDK];  // per-wave: v transposed VT[e][k']

    const int tid  = threadIdx.x;
    const int wv   = tid >> 6;
    const int lane = tid & 63;
    const int l16  = lane & 15;
    const int quad = lane >> 4;

    // ---- stage weights (transpose + cast to bf16), once per block ----
    const float* Ws[4] = {Wq, Wk, Wv, Wr};
    #pragma unroll
    for (int w = 0; w < 4; ++w) {
        const float* W = Ws[w];
        for (int i = tid; i < D * E; i += 256) {
            int dd = i >> 6;          // d (row of W)
            int e  = i & 63;          // e (col of W)
            WT[w][e * LDK + dd] = (bf16)W[i];
        }
    }
    // zero VT tail k' = 48..63 (never written by projections; must be 0 so
    // stale P cols 48..63 contribute nothing in the PV matmul)
    {
        bf16x8 z = {};
        *(bf16x8*)&VT[wv][lane * LDK + 48] = z;
        *(bf16x8*)&VT[wv][lane * LDK + 56] = z;
    }
    __syncthreads();

    for (int it = 0; it < ITER; ++it) {
        const int b = (blockIdx.x * WAVES + wv) * ITER + it;
        const float* Xb = X + (size_t)b * (F * D);

        // ---- load X A-fragments straight from global (fp32 -> bf16) ----
        bf16x8 xf[3][2];
        #pragma unroll
        for (int mt = 0; mt < 3; ++mt) {
            int row = mt * 16 + l16;
            if (row > F - 1) row = F - 1;          // clamp: no global OOB, finite pad rows
            #pragma unroll
            for (int kt = 0; kt < 2; ++kt) {
                const float* p = Xb + row * D + kt * 32 + quad * 8;
                float4 u0 = *(const float4*)p;
                float4 u1 = *(const float4*)(p + 4);
                bf16x8 f;
                f[0] = (bf16)u0.x; f[1] = (bf16)u0.y; f[2] = (bf16)u0.z; f[3] = (bf16)u0.w;
                f[4] = (bf16)u1.x; f[5] = (bf16)u1.y; f[6] = (bf16)u1.z; f[7] = (bf16)u1.w;
                xf[mt][kt] = f;
            }
        }

        // ---- projections q,k,v,r : [48x64] = X @ W ----
        f32x4 racc[3][4];
        #pragma unroll
        for (int w = 0; w < 4; ++w) {
            #pragma unroll
            for (int nt = 0; nt < 4; ++nt) {
                bf16x8 b0 = *(bf16x8*)&WT[w][(nt * 16 + l16) * LDK + 0  + quad * 8];
                bf16x8 b1 = *(bf16x8*)&WT[w][(nt * 16 + l16) * LDK + 32 + quad * 8];
                #pragma unroll
                for (int mt = 0; mt < 3; ++mt) {
                    f32x4 acc = {0.f, 0.f, 0.f, 0.f};
                    acc = __builtin_amdgcn_mfma_f32_16x16x32_bf16(xf[mt][0], b0, acc, 0, 0, 0);
                    acc = __builtin_amdgcn_mfma_f32_16x16x32_bf16(xf[mt][1], b1, acc, 0, 0, 0);
                    if (w == 3) {
                        racc[mt][nt] = acc;               // residual stays in registers
                    } else if (w == 2) {
                        // v: store transposed; 4 C-elements are contiguous in VT row
                        int col = nt * 16 + l16;
                        int r0  = mt * 16 + quad * 4;
                        bf16x4 pk;
                        pk[0] = (bf16)acc[0]; pk[1] = (bf16)acc[1];
                        pk[2] = (bf16)acc[2]; pk[3] = (bf16)acc[3];
                        *(bf16x4*)&VT[wv][col * LDK + r0] = pk;
                    } else {
                        bf16* dst = (w == 0) ? QB[wv] : KB[wv];
                        int col = nt * 16 + l16;
                        #pragma unroll
                        for (int r = 0; r < 4; ++r) {
                            int row = mt * 16 + quad * 4 + r;
                            if (row < F) dst[row * LDK + col] = (bf16)acc[r];
                        }
                    }
                }
            }
        }

        // ---- S = q @ k^T  [48x48], K=64 ----
        f32x4 sacc[3][3];
        bf16x8 kf[3][2];
        #pragma unroll
        for (int snt = 0; snt < 3; ++snt)
            #pragma unroll
            for (int kt = 0; kt < 2; ++kt)
                kf[snt][kt] = *(bf16x8*)&KB[wv][(snt * 16 + l16) * LDK + kt * 32 + quad * 8];
        #pragma unroll
        for (int smt = 0; smt < 3; ++smt) {
            bf16x8 q0 = *(bf16x8*)&QB[wv][(smt * 16 + l16) * LDK + 0  + quad * 8];
            bf16x8 q1 = *(bf16x8*)&QB[wv][(smt * 16 + l16) * LDK + 32 + quad * 8];
            #pragma unroll
            for (int snt = 0; snt < 3; ++snt) {
                f32x4 acc = {0.f, 0.f, 0.f, 0.f};
                acc = __builtin_amdgcn_mfma_f32_16x16x32_bf16(q0, kf[snt][0], acc, 0, 0, 0);
                acc = __builtin_amdgcn_mfma_f32_16x16x32_bf16(q1, kf[snt][1], acc, 0, 0, 0);
                sacc[smt][snt] = acc;
            }
        }

        // ---- softmax over cols (field-k axis); write P (bf16) into QB ----
        // lane holds S[row=smt*16+quad*4+r][col=snt*16+l16]; a row lives in the
        // 16 lanes sharing `quad` -> shfl_xor widths 1,2,4,8 reduce one row.
        const bool mask2 = (l16 >= 8);   // snt==2 covers cols 32..47; cols>=40 invalid
        #pragma unroll
        for (int smt = 0; smt < 3; ++smt) {
            #pragma unroll
            for (int r = 0; r < 4; ++r) {
                float s0 = sacc[smt][0][r];
                float s1 = sacc[smt][1][r];
                float s2 = mask2 ? -1e30f : sacc[smt][2][r];
                float m = fmaxf(fmaxf(s0, s1), s2);
                #pragma unroll
                for (int off = 1; off < 16; off <<= 1)
                    m = fmaxf(m, __shfl_xor(m, off, 64));
                float e0 = __expf(s0 - m);
                float e1 = __expf(s1 - m);
                float e2 = mask2 ? 0.f : __expf(s2 - m);
                float sum = e0 + e1 + e2;
                #pragma unroll
                for (int off = 1; off < 16; off <<= 1)
                    sum += __shfl_xor(sum, off, 64);
                float inv = 1.0f / sum;
                int row = smt * 16 + quad * 4 + r;
                if (row < F) {
                    QB[wv][row * LDK + l16]      = (bf16)(e0 * inv);
                    QB[wv][row * LDK + 16 + l16] = (bf16)(e1 * inv);
                    QB[wv][row * LDK + 32 + l16] = (bf16)(e2 * inv);  // exact 0 for cols>=40
                }
            }
        }

        // ---- O = P @ v + r, relu, store ----
        bf16x8 pf[3][2];
        #pragma unroll
        for (int mt = 0; mt < 3; ++mt)
            #pragma unroll
            for (int kt = 0; kt < 2; ++kt)
                pf[mt][kt] = *(bf16x8*)&QB[wv][(mt * 16 + l16) * LDK + kt * 32 + quad * 8];
        #pragma unroll
        for (int nt = 0; nt < 4; ++nt) {
            bf16x8 v0 = *(bf16x8*)&VT[wv][(nt * 16 + l16) * LDK + 0  + quad * 8];
            bf16x8 v1 = *(bf16x8*)&VT[wv][(nt * 16 + l16) * LDK + 32 + quad * 8];
            #pragma unroll
            for (int mt = 0; mt < 3; ++mt) {
                f32x4 acc = racc[mt][nt];   // residual as MFMA C-input
                acc = __builtin_amdgcn_mfma_f32_16x16x32_bf16(pf[mt][0], v0, acc, 0, 0, 0);
                acc = __builtin_amdgcn_mfma_f32_16x16x32_bf16(pf[mt][1], v1, acc, 0, 0, 0);
                int col = nt * 16 + l16;
                #pragma unroll
                for (int r = 0; r < 4; ++r) {
                    int row = mt * 16 + quad * 4 + r;
                    if (row < F)
                        Out[(size_t)b * (F * E) + row * E + col] = fmaxf(acc[r], 0.f);
                }
            }
        }
    }
}

extern "C" void kernel_launch(void* const* d_in, const int* in_sizes, int n_in,
                              void* d_out, int out_size, void* d_ws, size_t ws_size,
                              hipStream_t stream) {
    const float* X  = (const float*)d_in[0];
    const float* Wq = (const float*)d_in[1];
    const float* Wk = (const float*)d_in[2];
    const float* Wv = (const float*)d_in[3];
    const float* Wr = (const float*)d_in[4];
    float* Out = (float*)d_out;

    dim3 grid(BB / (WAVES * ITER));   // 1024 blocks, 4 waves each, 4 batches/wave
    attn_fused<<<grid, 256, 0, stream>>>(X, Wq, Wk, Wv, Wr, Out);
}